// Round 6
// baseline (21.839 us; speedup 1.0000x reference)
//
#include <hip/hip_runtime.h>

#define HH 512
#define WW 512
#define XG 128   // col groups  (WW/4)
#define YG 64    // row groups  (HH/8)
#define NXCD 8

__global__ __launch_bounds__(256) void median3_kernel(const float* __restrict__ x,
                                                      float* __restrict__ out,
                                                      int nimg, int cpx) {
    // XCD-aware swizzle (round-5 win): contiguous tile chunk per XCD so
    // vertical halo rows are L2 hits instead of second HBM fetches.
    int bid = blockIdx.x;
    int swz = (bid % NXCD) * cpx + bid / NXCD;
    int tid = swz * blockDim.x + threadIdx.x;

    int xg  = tid & (XG - 1);           // 4-col group
    int yg  = (tid >> 7) & (YG - 1);    // 8-row group
    int img = tid >> 13;
    if (img >= nimg) return;

    int y0 = yg << 3;
    int c0 = xg << 2;
    const float* p = x + (size_t)img * HH * WW;

    // 10 rows (y0-1 .. y0+8) x 6 cols (c0-1 .. c0+4), zero-padded at borders.
    // All 30 loads independent and issued up-front for MLP.
    float c[10][6];
#pragma unroll
    for (int dr = 0; dr < 10; ++dr) {
        int r = y0 + dr - 1;
        float4 m = make_float4(0.f, 0.f, 0.f, 0.f);
        float l = 0.f, rr = 0.f;
        if (r >= 0 && r < HH) {          // wave-uniform (yg constant per wave)
            const float* row = p + (size_t)r * WW + c0;
            m = *reinterpret_cast<const float4*>(row);
            if (xg > 0)      l  = row[-1];
            if (xg < XG - 1) rr = row[4];
        }
        c[dr][0] = l;
        c[dr][1] = m.x; c[dr][2] = m.y; c[dr][3] = m.z; c[dr][4] = m.w;
        c[dr][5] = rr;
    }

    float* outp = out + (size_t)img * HH * WW + (size_t)y0 * WW + c0;
#pragma unroll
    for (int t = 0; t < 8; ++t) {
        // sort each of the 6 columns of the 3-row window (t..t+2)
        float lo[6], mi[6], hi[6];
#pragma unroll
        for (int j = 0; j < 6; ++j) {
            float a = c[t][j], b = c[t + 1][j], d = c[t + 2][j];
            lo[j] = fminf(fminf(a, b), d);
            hi[j] = fmaxf(fmaxf(a, b), d);
            mi[j] = __builtin_amdgcn_fmed3f(a, b, d);
        }
        // Smith: median9 = med3(max3(lows), med3(mids), min3(highs))
        float4 o;
        float* op = &o.x;
#pragma unroll
        for (int j = 0; j < 4; ++j) {
            float mx = fmaxf(fmaxf(lo[j], lo[j + 1]), lo[j + 2]);
            float md = __builtin_amdgcn_fmed3f(mi[j], mi[j + 1], mi[j + 2]);
            float mn = fminf(fminf(hi[j], hi[j + 1]), hi[j + 2]);
            op[j] = __builtin_amdgcn_fmed3f(mx, md, mn);
        }
        *reinterpret_cast<float4*>(outp + (size_t)t * WW) = o;
    }
}

extern "C" void kernel_launch(void* const* d_in, const int* in_sizes, int n_in,
                              void* d_out, int out_size, void* d_ws, size_t ws_size,
                              hipStream_t stream) {
    const float* x = (const float*)d_in[0];
    float* out = (float*)d_out;
    int nimg = in_sizes[0] / (HH * WW);          // 16 * 3 = 48
    int total_threads = nimg * YG * XG;          // one thread per 4x8 output tile
    int block = 256;
    int grid = (total_threads + block - 1) / block;   // 1536, divisible by 8
    int cpx = grid / NXCD;
    median3_kernel<<<grid, block, 0, stream>>>(x, out, nimg, cpx);
}

// Round 8
// 20.722 us; speedup vs baseline: 1.0539x; 1.0539x over previous
//
#include <hip/hip_runtime.h>

#define HH 512
#define WW 512
#define XG 128   // col groups  (WW/4)
#define YG 128   // row groups  (HH/4)
#define NXCD 8

typedef float f32x4 __attribute__((ext_vector_type(4)));

__global__ __launch_bounds__(256) void median3_kernel(const float* __restrict__ x,
                                                      float* __restrict__ out,
                                                      int nimg, int cpx) {
    // XCD-aware swizzle (round-5 win): contiguous tile chunk per XCD so
    // vertical halo rows are L2 hits instead of second HBM fetches.
    int bid = blockIdx.x;
    int swz = (bid % NXCD) * cpx + bid / NXCD;
    int tid = swz * blockDim.x + threadIdx.x;

    int xg  = tid & (XG - 1);           // 4-col group
    int yg  = (tid >> 7) & (YG - 1);    // 4-row group
    int img = tid >> 14;
    if (img >= nimg) return;

    int y0 = yg << 2;
    int c0 = xg << 2;
    const float* p = x + (size_t)img * HH * WW;

    // 6 rows (y0-1 .. y0+4) x 6 cols (c0-1 .. c0+4), zero-padded at borders
    float c[6][6];
#pragma unroll
    for (int dr = 0; dr < 6; ++dr) {
        int r = y0 + dr - 1;
        float4 m = make_float4(0.f, 0.f, 0.f, 0.f);
        float l = 0.f, rr = 0.f;
        if (r >= 0 && r < HH) {          // wave-uniform (yg constant per wave)
            const float* row = p + (size_t)r * WW + c0;
            m = *reinterpret_cast<const float4*>(row);
            if (xg > 0)      l  = row[-1];
            if (xg < XG - 1) rr = row[4];
        }
        c[dr][0] = l;
        c[dr][1] = m.x; c[dr][2] = m.y; c[dr][3] = m.z; c[dr][4] = m.w;
        c[dr][5] = rr;
    }

    float* outp = out + (size_t)img * HH * WW + (size_t)y0 * WW + c0;
#pragma unroll
    for (int t = 0; t < 4; ++t) {
        // sort each of the 6 columns of the 3-row window (t..t+2)
        float lo[6], mi[6], hi[6];
#pragma unroll
        for (int j = 0; j < 6; ++j) {
            float a = c[t][j], b = c[t + 1][j], d = c[t + 2][j];
            lo[j] = fminf(fminf(a, b), d);
            hi[j] = fmaxf(fmaxf(a, b), d);
            mi[j] = __builtin_amdgcn_fmed3f(a, b, d);
        }
        // Smith: median9 = med3(max3(lows), med3(mids), min3(highs))
        f32x4 o;
#pragma unroll
        for (int j = 0; j < 4; ++j) {
            float mx = fmaxf(fmaxf(lo[j], lo[j + 1]), lo[j + 2]);
            float md = __builtin_amdgcn_fmed3f(mi[j], mi[j + 1], mi[j + 2]);
            float mn = fminf(fminf(hi[j], hi[j + 1]), hi[j + 2]);
            o[j] = __builtin_amdgcn_fmed3f(mx, md, mn);
        }
        // Non-temporal: output is never re-read; keep it out of L2 so the
        // input halo rows stay resident (swizzle makes them same-XCD).
        __builtin_nontemporal_store(o, reinterpret_cast<f32x4*>(outp + (size_t)t * WW));
    }
}

extern "C" void kernel_launch(void* const* d_in, const int* in_sizes, int n_in,
                              void* d_out, int out_size, void* d_ws, size_t ws_size,
                              hipStream_t stream) {
    const float* x = (const float*)d_in[0];
    float* out = (float*)d_out;
    int nimg = in_sizes[0] / (HH * WW);          // 16 * 3 = 48
    int total_threads = nimg * YG * XG;          // one thread per 4x4 output tile
    int block = 256;
    int grid = (total_threads + block - 1) / block;   // 3072, divisible by 8
    int cpx = grid / NXCD;
    median3_kernel<<<grid, block, 0, stream>>>(x, out, nimg, cpx);
}